// Round 4
// baseline (449.675 us; speedup 1.0000x reference)
//
#include <hip/hip_runtime.h>

// Problem constants (match reference)
#define D     4
#define MUL   16
#define S0    8
#define S1    8
#define SOUT  8
#define NP3   8
#define NP4   4

#define EPB   16          // edges per block (4 per wave)
#define TPB   256
#define WSTRIDE 200       // 192 entries + 8 pad; 16B-aligned rows, conflict-free

// Edge bucketing: i0 in [0, 50000) -> bucket = i0>>6 (0..781), 1024 bins.
// Edges sorted by bucket => x0 gather walks ascending ~100KB windows; both
// touches of a row (avg multiplicity 2) land in the same bucket -> L2/L3 hits.
#define BINS      1024
#define BIN_SHIFT 6
#define NXCD      8

// Wave-scope LDS ordering (producers/consumers of a Wt row are the same wave).
__device__ __forceinline__ void wave_lds_fence() {
    __builtin_amdgcn_fence(__ATOMIC_RELEASE, "wavefront");
    __builtin_amdgcn_wave_barrier();
    __builtin_amdgcn_fence(__ATOMIC_ACQUIRE, "wavefront");
}

__device__ __forceinline__ float4 sel8(const float4 (&a)[8], int s) {
    switch (s & 7) {
        case 0: return a[0];
        case 1: return a[1];
        case 2: return a[2];
        case 3: return a[3];
        case 4: return a[4];
        case 5: return a[5];
        case 6: return a[6];
        default: return a[7];
    }
}

#define ADDC(idx) acc[idx].x += cv.x; acc[idx].y += cv.y; acc[idx].z += cv.z; acc[idx].w += cv.w; break;
__device__ __forceinline__ void addsel8(float4 (&acc)[8], int s, float4 cv) {
    switch (s & 7) {
        case 0: ADDC(0)
        case 1: ADDC(1)
        case 2: ADDC(2)
        case 3: ADDC(3)
        case 4: ADDC(4)
        case 5: ADDC(5)
        case 6: ADDC(6)
        default: ADDC(7)
    }
}

// ---------------- bucket-sort pre-pass (4 tiny dispatches) ----------------

__global__ void zero_hist_kernel(int* __restrict__ hist) {
    hist[threadIdx.x] = 0;          // 1 block x BINS
}

__global__ void hist_kernel(const int* __restrict__ i0, int E,
                            int* __restrict__ hist) {
    __shared__ int h[BINS];
    for (int i = threadIdx.x; i < BINS; i += blockDim.x) h[i] = 0;
    __syncthreads();
    for (long e = (long)blockIdx.x * blockDim.x + threadIdx.x; e < E;
         e += (long)gridDim.x * blockDim.x)
        atomicAdd(&h[((unsigned)i0[e]) >> BIN_SHIFT], 1);
    __syncthreads();
    for (int i = threadIdx.x; i < BINS; i += blockDim.x)
        if (h[i]) atomicAdd(&hist[i], h[i]);
}

__global__ void scan_kernel(const int* __restrict__ hist,
                            int* __restrict__ cursor) {
    __shared__ int t[BINS];
    const int i = threadIdx.x;      // BINS threads
    const int self = hist[i];
    t[i] = self;
    for (int d = 1; d < BINS; d <<= 1) {
        __syncthreads();
        const int v = (i >= d) ? t[i - d] : 0;
        __syncthreads();
        t[i] += v;
    }
    __syncthreads();
    cursor[i] = t[i] - self;        // exclusive prefix -> running cursor
}

__global__ void scatter_kernel(const int* __restrict__ i0, int E,
                               int* __restrict__ cursor,
                               int* __restrict__ perm,
                               int* __restrict__ prow) {
    for (long e = (long)blockIdx.x * blockDim.x + threadIdx.x; e < E;
         e += (long)gridDim.x * blockDim.x) {
        const int r = i0[e];
        const int pos = atomicAdd(&cursor[((unsigned)r) >> BIN_SHIFT], 1);
        perm[pos] = (int)e;
        prow[pos] = r;
    }
}

// ---------------- main kernel (R1 structure + permuted edge order) ----------------

__global__ __launch_bounds__(TPB)
void tp_fused_kernel(const float* __restrict__ x0,
                     const int*   __restrict__ i0,
                     const float* __restrict__ x1,
                     const float* __restrict__ C3,
                     const float* __restrict__ C4,
                     const int*   __restrict__ p3,
                     const int*   __restrict__ p4,
                     float*       __restrict__ out,
                     const int*   __restrict__ perm,   // may be null
                     const int*   __restrict__ prow,   // may be null
                     int E, int nwg)
{
    __shared__ float Wt[EPB * WSTRIDE];

    // Bijective XCD swizzle: same-bucket (consecutive) blocks share an XCD L2.
    int bid = blockIdx.x;
    {
        const int q = nwg / NXCD, r = nwg % NXCD;
        const int xcd = bid % NXCD, idx = bid / NXCD;
        bid = (xcd < r ? xcd * (q + 1) : r * (q + 1) + (xcd - r) * q) + idx;
    }

    const int tid = threadIdx.x;
    const int eL  = tid >> 4;        // local edge 0..15
    const int u   = tid & 15;        // mul channel 0..15
    const long e  = (long)bid * EPB + eL;
    const bool ev = (e < (long)E);
    const long ec = ev ? e : (long)(E - 1);

    // Edge identity: sorted order if perm given (uniform branch).
    int eidx, row;
    if (perm != nullptr) {
        eidx = perm[ec];             // broadcast within the 16-lane edge group
        row  = prow[ec];
    } else {
        eidx = (int)ec;
        row  = i0[ec];
    }

    // ---------- issue the long-latency gather chain FIRST ----------
    const float4* ar = (const float4*)(x0 + (long)row * (S0 * MUL * D));
    float4 a[S0];
    #pragma unroll
    for (int s = 0; s < S0; ++s) a[s] = ar[s * MUL + u];

    // ---------- path metadata ----------
    int q3s0[NP3], q3s1[NP3], q3so[NP3];
    #pragma unroll
    for (int p = 0; p < NP3; ++p) {
        q3s0[p] = p3[p * 3 + 0];
        q3s1[p] = p3[p * 3 + 1];
        q3so[p] = p3[p * 3 + 2];
    }
    int q4s0[NP4], q4s1[NP4], q4s2[NP4], q4so[NP4];
    #pragma unroll
    for (int p = 0; p < NP4; ++p) {
        q4s0[p] = p4[p * 4 + 0];
        q4s1[p] = p4[p * 4 + 1];
        q4s2[p] = p4[p * 4 + 2];
        q4so[p] = p4[p * 4 + 3];
    }

    // ---------- per-edge weight matrices (overlaps gather latency) ----------
    const float* x1r = x1 + (long)eidx * (S1 * D);
    const int iu = u >> 2, ku = u & 3;
    float* wr = &Wt[eL * WSTRIDE];

    #pragma unroll
    for (int p = 0; p < NP3; ++p) {
        const float4 b = *(const float4*)(x1r + q3s1[p] * D);
        const float* c3 = C3 + p * 64 + iu * 16 + ku;   // + j*4
        wr[p * 16 + u] = b.x * c3[0] + b.y * c3[4] + b.z * c3[8] + b.w * c3[12];
    }
    #pragma unroll
    for (int p = 0; p < NP4; ++p) {
        const float4 b = *(const float4*)(x1r + q4s1[p] * D);
        const float4 c = *(const float4*)(x1r + q4s2[p] * D);
        const float* c4 = C4 + p * 256 + iu * 64 + ku;  // + j*16 + k*4
        float s = 0.f;
        const float bj[4] = {b.x, b.y, b.z, b.w};
        const float ck[4] = {c.x, c.y, c.z, c.w};
        #pragma unroll
        for (int j = 0; j < 4; ++j) {
            #pragma unroll
            for (int k = 0; k < 4; ++k)
                s += bj[j] * ck[k] * c4[j * 16 + k * 4];
        }
        wr[128 + p * 16 + u] = s;
    }

    wave_lds_fence();

    // ---------- contributions ----------
    float4 acc[SOUT];
    #pragma unroll
    for (int s = 0; s < SOUT; ++s) acc[s] = make_float4(0.f, 0.f, 0.f, 0.f);

    #pragma unroll
    for (int p = 0; p < NP3 + NP4; ++p) {
        const int s0s = (p < NP3) ? q3s0[p] : q4s0[p - NP3];
        const int os  = (p < NP3) ? q3so[p] : q4so[p - NP3];
        const float4 av = sel8(a, s0s);
        const float4 w0 = *(const float4*)(wr + p * 16 + 0);
        const float4 w1 = *(const float4*)(wr + p * 16 + 4);
        const float4 w2 = *(const float4*)(wr + p * 16 + 8);
        const float4 w3v = *(const float4*)(wr + p * 16 + 12);
        float4 cv;
        cv.x = av.x * w0.x + av.y * w1.x + av.z * w2.x + av.w * w3v.x;
        cv.y = av.x * w0.y + av.y * w1.y + av.z * w2.y + av.w * w3v.y;
        cv.z = av.x * w0.z + av.y * w1.z + av.z * w2.z + av.w * w3v.z;
        cv.w = av.x * w0.w + av.y * w1.w + av.z * w2.w + av.w * w3v.w;
        addsel8(acc, os, cv);
    }

    // ---------- coalesced write-back store (permuted 2KB rows; full coverage) ----------
    if (ev) {
        float* o = out + (long)eidx * (SOUT * MUL * D);
        #pragma unroll
        for (int s = 0; s < SOUT; ++s) {
            *(float4*)(o + (s * MUL + u) * D) = acc[s];
        }
    }
}

extern "C" void kernel_launch(void* const* d_in, const int* in_sizes, int n_in,
                              void* d_out, int out_size, void* d_ws, size_t ws_size,
                              hipStream_t stream) {
    const float* x0 = (const float*)d_in[0];
    const int*   i0 = (const int*)  d_in[1];
    const float* x1 = (const float*)d_in[2];
    const float* C3 = (const float*)d_in[3];
    const float* C4 = (const float*)d_in[4];
    const int*   p3 = (const int*)  d_in[5];
    const int*   p4 = (const int*)  d_in[6];
    float* out = (float*)d_out;

    const int E = in_sizes[1];                 // i0 has E elements
    const int blocks = (E + EPB - 1) / EPB;

    const size_t need = (size_t)(2 * BINS + 2 * (size_t)E) * sizeof(int);
    if (d_ws != nullptr && ws_size >= need) {
        int* hist   = (int*)d_ws;
        int* cursor = hist + BINS;
        int* perm   = cursor + BINS;
        int* prow   = perm + E;

        zero_hist_kernel<<<1, BINS, 0, stream>>>(hist);
        hist_kernel<<<256, 256, 0, stream>>>(i0, E, hist);
        scan_kernel<<<1, BINS, 0, stream>>>(hist, cursor);
        scatter_kernel<<<256, 256, 0, stream>>>(i0, E, cursor, perm, prow);
        tp_fused_kernel<<<blocks, TPB, 0, stream>>>(x0, i0, x1, C3, C4, p3, p4,
                                                    out, perm, prow, E, blocks);
    } else {
        tp_fused_kernel<<<blocks, TPB, 0, stream>>>(x0, i0, x1, C3, C4, p3, p4,
                                                    out, nullptr, nullptr, E, blocks);
    }
}

// Round 5
// 393.130 us; speedup vs baseline: 1.1438x; 1.1438x over previous
//
#include <hip/hip_runtime.h>

// Problem constants (match reference)
#define D     4
#define MUL   16
#define S0    8
#define S1    8
#define SOUT  8
#define NP3   8
#define NP4   4

#define EPB   16          // edges per block (4 per wave)
#define TPB   256
// Wt row stride per edge: 192 entries + 8 pad = 200 floats = 800 B.
// 800 B is 16B-aligned (ds_*_b128 ok); 200 % 32 == 8 -> the 4 edges of a wave
// start 8 banks apart -> b128 broadcast reads are conflict-free.
#define WSTRIDE 200

// Wave-scope LDS ordering: producers and consumers of each Wt row are the SAME
// wave (edge eL's 16 threads all live in wave eL>>2), and DS ops from one wave
// execute in order. We only need to stop the compiler from reordering.
__device__ __forceinline__ void wave_lds_fence() {
    __builtin_amdgcn_fence(__ATOMIC_RELEASE, "wavefront");
    __builtin_amdgcn_wave_barrier();
    __builtin_amdgcn_fence(__ATOMIC_ACQUIRE, "wavefront");
}

__device__ __forceinline__ float4 sel8(const float4 (&a)[8], int s) {
    // s is wave-uniform (SGPR metadata) -> scalar branch tree; every array
    // index inside a case is a compile-time constant (no scratch risk).
    switch (s & 7) {
        case 0: return a[0];
        case 1: return a[1];
        case 2: return a[2];
        case 3: return a[3];
        case 4: return a[4];
        case 5: return a[5];
        case 6: return a[6];
        default: return a[7];
    }
}

#define ADDC4(idx) acc[idx].x += cv.x; acc[idx].y += cv.y; acc[idx].z += cv.z; acc[idx].w += cv.w; break;
__device__ __forceinline__ void addsel4(float4 (&acc)[4], int s, float4 cv) {
    switch (s & 3) {
        case 0: ADDC4(0)
        case 1: ADDC4(1)
        case 2: ADDC4(2)
        default: ADDC4(3)
    }
}

// 4 waves/EU floor -> VGPR cap 128: the two-phase structure peaks at ~75 live
// VGPRs (a[8]=32 + acc[4]=16 + transients), so the allocator can keep
// EVERYTHING resident -- no scratch, no serialized reloads.
__global__ __launch_bounds__(TPB, 4)
void tp_fused_kernel(const float* __restrict__ x0,
                     const int*   __restrict__ i0,
                     const float* __restrict__ x1,
                     const float* __restrict__ C3,
                     const float* __restrict__ C4,
                     const int*   __restrict__ p3,
                     const int*   __restrict__ p4,
                     float*       __restrict__ out,
                     int E)
{
    __shared__ float Wt[EPB * WSTRIDE];

    const int tid = threadIdx.x;
    const int eL  = tid >> 4;        // local edge 0..15
    const int u   = tid & 15;        // mul channel 0..15
    const long e  = (long)blockIdx.x * EPB + eL;
    const bool ev = (e < (long)E);
    const long ec = ev ? e : (long)(E - 1);

    // ---------- issue the long-latency gather chain FIRST ----------
    const int row = i0[ec];
    const float4* ar = (const float4*)(x0 + (long)row * (S0 * MUL * D));
    float4 a[S0];
    #pragma unroll
    for (int s = 0; s < S0; ++s) a[s] = ar[s * MUL + u];

    // ---------- path metadata: uniform addresses -> s_load into SGPRs ----------
    int q3s0[NP3], q3s1[NP3], q3so[NP3];
    #pragma unroll
    for (int p = 0; p < NP3; ++p) {
        q3s0[p] = p3[p * 3 + 0];
        q3s1[p] = p3[p * 3 + 1];
        q3so[p] = p3[p * 3 + 2];
    }
    int q4s0[NP4], q4s1[NP4], q4s2[NP4], q4so[NP4];
    #pragma unroll
    for (int p = 0; p < NP4; ++p) {
        q4s0[p] = p4[p * 4 + 0];
        q4s1[p] = p4[p * 4 + 1];
        q4s2[p] = p4[p * 4 + 2];
        q4so[p] = p4[p * 4 + 3];
    }

    // ---------- per-edge weight matrices (overlaps gather latency) ----------
    // Lane u computes entry r=u of each path's 16-entry (i x k) weight block.
    // Stage ALL x1 vectors for a phase first (parallel independent loads),
    // THEN do the math -- no load->use->load->use serialization.
    const float* x1r = x1 + ec * (S1 * D);
    const int iu = u >> 2, ku = u & 3;
    float* wr = &Wt[eL * WSTRIDE];

    {
        float4 b[NP3];
        #pragma unroll
        for (int p = 0; p < NP3; ++p)
            b[p] = *(const float4*)(x1r + q3s1[p] * D);
        #pragma unroll
        for (int p = 0; p < NP3; ++p) {
            const float* c3 = C3 + p * 64 + iu * 16 + ku;   // + j*4
            wr[p * 16 + u] = b[p].x * c3[0] + b[p].y * c3[4]
                           + b[p].z * c3[8] + b[p].w * c3[12];
        }
    }
    {
        float4 b[NP4], c[NP4];
        #pragma unroll
        for (int p = 0; p < NP4; ++p) {
            b[p] = *(const float4*)(x1r + q4s1[p] * D);
            c[p] = *(const float4*)(x1r + q4s2[p] * D);
        }
        #pragma unroll
        for (int p = 0; p < NP4; ++p) {
            const float* c4 = C4 + p * 256 + iu * 64 + ku;  // + j*16 + k*4
            float s = 0.f;
            const float bj[4] = {b[p].x, b[p].y, b[p].z, b[p].w};
            const float ck[4] = {c[p].x, c[p].y, c[p].z, c[p].w};
            #pragma unroll
            for (int j = 0; j < 4; ++j) {
                #pragma unroll
                for (int k = 0; k < 4; ++k)
                    s += bj[j] * ck[k] * c4[j * 16 + k * 4];
            }
            wr[128 + p * 16 + u] = s;
        }
    }

    wave_lds_fence();   // same-wave producers/consumers; no s_barrier, no vmcnt drain

    // ---------- contributions: two output-slot halves ----------
    // Half h accumulates paths with os in [4h, 4h+4) into acc[4] and stores
    // those 4 sout slots immediately. Peak live: a[8](32) + acc[4](16) +
    // transients -> no 64-reg dual-array live range, nothing spillable.
    float* o = out + e * (SOUT * MUL * D);

    #pragma unroll
    for (int h = 0; h < 2; ++h) {
        float4 acc[4];
        #pragma unroll
        for (int s = 0; s < 4; ++s) acc[s] = make_float4(0.f, 0.f, 0.f, 0.f);

        #pragma unroll
        for (int p = 0; p < NP3 + NP4; ++p) {
            const int s0s = (p < NP3) ? q3s0[p] : q4s0[p - NP3];
            const int os  = (p < NP3) ? q3so[p] : q4so[p - NP3];
            if ((os >> 2) == h) {               // wave-uniform branch (SGPR)
                const float4 av = sel8(a, s0s);
                const float4 w0  = *(const float4*)(wr + p * 16 + 0);
                const float4 w1  = *(const float4*)(wr + p * 16 + 4);
                const float4 w2  = *(const float4*)(wr + p * 16 + 8);
                const float4 w3v = *(const float4*)(wr + p * 16 + 12);
                float4 cv;
                cv.x = av.x * w0.x + av.y * w1.x + av.z * w2.x + av.w * w3v.x;
                cv.y = av.x * w0.y + av.y * w1.y + av.z * w2.y + av.w * w3v.y;
                cv.z = av.x * w0.z + av.y * w1.z + av.z * w2.z + av.w * w3v.z;
                cv.w = av.x * w0.w + av.y * w1.w + av.z * w2.w + av.w * w3v.w;
                addsel4(acc, os, cv);
            }
        }

        if (ev) {
            #pragma unroll
            for (int s = 0; s < 4; ++s) {
                *(float4*)(o + ((h * 4 + s) * MUL + u) * D) = acc[s];
            }
        }
    }
}

extern "C" void kernel_launch(void* const* d_in, const int* in_sizes, int n_in,
                              void* d_out, int out_size, void* d_ws, size_t ws_size,
                              hipStream_t stream) {
    const float* x0 = (const float*)d_in[0];
    const int*   i0 = (const int*)  d_in[1];
    const float* x1 = (const float*)d_in[2];
    const float* C3 = (const float*)d_in[3];
    const float* C4 = (const float*)d_in[4];
    const int*   p3 = (const int*)  d_in[5];
    const int*   p4 = (const int*)  d_in[6];
    float* out = (float*)d_out;

    const int E = in_sizes[1];                 // i0 has E elements
    const int blocks = (E + EPB - 1) / EPB;
    tp_fused_kernel<<<blocks, TPB, 0, stream>>>(x0, i0, x1, C3, C4, p3, p4, out, E);
}

// Round 6
// 376.324 us; speedup vs baseline: 1.1949x; 1.0447x over previous
//
#include <hip/hip_runtime.h>

// Problem constants (match reference)
#define D     4
#define MUL   16
#define S0    8
#define S1    8
#define SOUT  8
#define NP3   8
#define NP4   4

#define EPB   16          // edges per block (4 per wave)
#define TPB   256
// Wt row stride per edge: 192 entries + 8 pad = 200 floats = 800 B.
#define WSTRIDE 200

// Wave-scope LDS ordering: producers and consumers of each Wt row are the SAME
// wave (edge eL's 16 threads all live in wave eL>>2), and DS ops from one wave
// execute in order. We only need to stop the compiler from reordering.
__device__ __forceinline__ void wave_lds_fence() {
    __builtin_amdgcn_fence(__ATOMIC_RELEASE, "wavefront");
    __builtin_amdgcn_wave_barrier();
    __builtin_amdgcn_fence(__ATOMIC_ACQUIRE, "wavefront");
}

// DPP quad butterfly add: sums over the 4 lanes of each quad (lane&3 = j).
// quad_perm[1,0,3,2] = 0xB1 (xor 1), quad_perm[2,3,0,1] = 0x4E (xor 2).
// Pure VALU (no DS pipe); all lanes active so bound_ctrl never triggers.
__device__ __forceinline__ float dpp_add_xor1(float v) {
    int y = __builtin_amdgcn_update_dpp(0, __float_as_int(v), 0xB1, 0xF, 0xF, true);
    return v + __int_as_float(y);
}
__device__ __forceinline__ float dpp_add_xor2(float v) {
    int y = __builtin_amdgcn_update_dpp(0, __float_as_int(v), 0x4E, 0xF, 0xF, true);
    return v + __int_as_float(y);
}
__device__ __forceinline__ float4 quad_sum4(float4 v) {
    v.x = dpp_add_xor1(v.x); v.y = dpp_add_xor1(v.y);
    v.z = dpp_add_xor1(v.z); v.w = dpp_add_xor1(v.w);
    v.x = dpp_add_xor2(v.x); v.y = dpp_add_xor2(v.y);
    v.z = dpp_add_xor2(v.z); v.w = dpp_add_xor2(v.w);
    return v;
}

// Per-lane component select v[j] (j divergent) -> 3 v_cndmask, no scratch.
__device__ __forceinline__ float comp_sel(float4 v, int j) {
    const float lo = (j & 1) ? v.y : v.x;
    const float hi = (j & 1) ? v.w : v.z;
    return (j & 2) ? hi : lo;
}

__device__ __forceinline__ float4 sel8(const float4 (&a)[8], int s) {
    // s is wave-uniform (SGPR metadata) -> scalar branch tree; compile-time
    // constant indices inside cases (no scratch risk).
    switch (s & 7) {
        case 0: return a[0];
        case 1: return a[1];
        case 2: return a[2];
        case 3: return a[3];
        case 4: return a[4];
        case 5: return a[5];
        case 6: return a[6];
        default: return a[7];
    }
}

#define ADDC4(idx) acc[idx].x += cv.x; acc[idx].y += cv.y; acc[idx].z += cv.z; acc[idx].w += cv.w; break;
__device__ __forceinline__ void addsel4(float4 (&acc)[4], int s, float4 cv) {
    switch (s & 3) {
        case 0: ADDC4(0)
        case 1: ADDC4(1)
        case 2: ADDC4(2)
        default: ADDC4(3)
    }
}

// 4 waves/EU floor -> VGPR cap 128: peak live ~80 (a[8]=32 + C4 transients),
// keeps everything resident -- no scratch (R5 lesson).
__global__ __launch_bounds__(TPB, 4)
void tp_fused_kernel(const float* __restrict__ x0,
                     const int*   __restrict__ i0,
                     const float* __restrict__ x1,
                     const float* __restrict__ C3,
                     const float* __restrict__ C4,
                     const int*   __restrict__ p3,
                     const int*   __restrict__ p4,
                     float*       __restrict__ out,
                     int E)
{
    __shared__ float Wt[EPB * WSTRIDE];

    const int tid = threadIdx.x;
    const int eL  = tid >> 4;        // local edge 0..15
    const int u   = tid & 15;        // mul channel 0..15
    const long e  = (long)blockIdx.x * EPB + eL;
    const bool ev = (e < (long)E);
    const long ec = ev ? e : (long)(E - 1);

    // ---------- issue the long-latency gather chain FIRST ----------
    const int row = i0[ec];
    const float4* ar = (const float4*)(x0 + (long)row * (S0 * MUL * D));
    float4 a[S0];
    #pragma unroll
    for (int s = 0; s < S0; ++s) a[s] = ar[s * MUL + u];

    // ---------- path metadata: uniform addresses -> s_load into SGPRs ----------
    int q3s0[NP3], q3s1[NP3], q3so[NP3];
    #pragma unroll
    for (int p = 0; p < NP3; ++p) {
        q3s0[p] = p3[p * 3 + 0];
        q3s1[p] = p3[p * 3 + 1];
        q3so[p] = p3[p * 3 + 2];
    }
    int q4s0[NP4], q4s1[NP4], q4s2[NP4], q4so[NP4];
    #pragma unroll
    for (int p = 0; p < NP4; ++p) {
        q4s0[p] = p4[p * 4 + 0];
        q4s1[p] = p4[p * 4 + 1];
        q4s2[p] = p4[p * 4 + 2];
        q4so[p] = p4[p * 4 + 3];
    }

    // ---------- per-edge weight matrices (overlaps gather latency) ----------
    // Lane-cooperative C loads: lane u owns (i=u>>2, j=u&3) and loads the
    // CONTIGUOUS float4 over the trailing dim -> 1 vector load replaces 4
    // scalars (C3) / 4 vector loads replace 16 scalars (C4). Sum over j via
    // quad DPP butterfly; lane j==0 writes the reduced row. Same Wt layout.
    const float* x1r = x1 + ec * (S1 * D);
    const int j  = u & 3;
    const int iu = u >> 2;
    float* wr = &Wt[eL * WSTRIDE];

    #pragma unroll
    for (int p = 0; p < NP3; ++p) {
        const float4 b   = *(const float4*)(x1r + q3s1[p] * D);
        const float4 c3v = *(const float4*)(C3 + p * 64 + u * 4); // C3[p][i][j][:]
        const float bs = comp_sel(b, j);
        float4 part = make_float4(bs * c3v.x, bs * c3v.y, bs * c3v.z, bs * c3v.w);
        part = quad_sum4(part);                   // sum over j across the quad
        if (j == 0) *(float4*)(wr + p * 16 + iu * 4) = part;  // W3[i][k=0..3]
    }
    #pragma unroll
    for (int p = 0; p < NP4; ++p) {
        const float4 b = *(const float4*)(x1r + q4s1[p] * D);
        const float4 c = *(const float4*)(x1r + q4s2[p] * D);
        const float* c4 = C4 + p * 256 + u * 16;  // C4[p][i][j][k][:], 64B/lane
        const float4 v0 = *(const float4*)(c4 + 0);
        const float4 v1 = *(const float4*)(c4 + 4);
        const float4 v2 = *(const float4*)(c4 + 8);
        const float4 v3 = *(const float4*)(c4 + 12);
        // k-contraction in registers (c components are static -> no selects)
        float4 t;
        t.x = c.x * v0.x + c.y * v1.x + c.z * v2.x + c.w * v3.x;
        t.y = c.x * v0.y + c.y * v1.y + c.z * v2.y + c.w * v3.y;
        t.z = c.x * v0.z + c.y * v1.z + c.z * v2.z + c.w * v3.z;
        t.w = c.x * v0.w + c.y * v1.w + c.z * v2.w + c.w * v3.w;
        const float bs = comp_sel(b, j);
        t.x *= bs; t.y *= bs; t.z *= bs; t.w *= bs;
        t = quad_sum4(t);                          // sum over j across the quad
        if (j == 0) *(float4*)(wr + 128 + p * 16 + iu * 4) = t;  // W4[i][m]
    }

    wave_lds_fence();   // same-wave producers/consumers; no s_barrier, no vmcnt drain

    // ---------- contributions: two output-slot halves (R5 structure) ----------
    float* o = out + e * (SOUT * MUL * D);

    #pragma unroll
    for (int h = 0; h < 2; ++h) {
        float4 acc[4];
        #pragma unroll
        for (int s = 0; s < 4; ++s) acc[s] = make_float4(0.f, 0.f, 0.f, 0.f);

        #pragma unroll
        for (int p = 0; p < NP3 + NP4; ++p) {
            const int s0s = (p < NP3) ? q3s0[p] : q4s0[p - NP3];
            const int os  = (p < NP3) ? q3so[p] : q4so[p - NP3];
            if ((os >> 2) == h) {               // wave-uniform branch (SGPR)
                const float4 av = sel8(a, s0s);
                const float4 w0  = *(const float4*)(wr + p * 16 + 0);
                const float4 w1  = *(const float4*)(wr + p * 16 + 4);
                const float4 w2  = *(const float4*)(wr + p * 16 + 8);
                const float4 w3v = *(const float4*)(wr + p * 16 + 12);
                float4 cv;
                cv.x = av.x * w0.x + av.y * w1.x + av.z * w2.x + av.w * w3v.x;
                cv.y = av.x * w0.y + av.y * w1.y + av.z * w2.y + av.w * w3v.y;
                cv.z = av.x * w0.z + av.y * w1.z + av.z * w2.z + av.w * w3v.z;
                cv.w = av.x * w0.w + av.y * w1.w + av.z * w2.w + av.w * w3v.w;
                addsel4(acc, os, cv);
            }
        }

        if (ev) {
            #pragma unroll
            for (int s = 0; s < 4; ++s) {
                *(float4*)(o + ((h * 4 + s) * MUL + u) * D) = acc[s];
            }
        }
    }
}

extern "C" void kernel_launch(void* const* d_in, const int* in_sizes, int n_in,
                              void* d_out, int out_size, void* d_ws, size_t ws_size,
                              hipStream_t stream) {
    const float* x0 = (const float*)d_in[0];
    const int*   i0 = (const int*)  d_in[1];
    const float* x1 = (const float*)d_in[2];
    const float* C3 = (const float*)d_in[3];
    const float* C4 = (const float*)d_in[4];
    const int*   p3 = (const int*)  d_in[5];
    const int*   p4 = (const int*)  d_in[6];
    float* out = (float*)d_out;

    const int E = in_sizes[1];                 // i0 has E elements
    const int blocks = (E + EPB - 1) / EPB;
    tp_fused_kernel<<<blocks, TPB, 0, stream>>>(x0, i0, x1, C3, C4, p3, p4, out, E);
}